// Round 12
// baseline (298.155 us; speedup 1.0000x reference)
//
#include <hip/hip_runtime.h>

// Problem constants (fixed by the reference)
#define Bn   4
#define Tn   512
#define Pn   3
#define HIDn 512
#define HDn  32
#define Hn   16
#define EXPn 512
#define Sn   1024
#define Dn   96          // per-head dim = P*HD
#define LOG2E 1.44269504088896340736f
#define CH   32          // s-cols per chunk
#define NCH  (Sn / CH)   // 32 chunks

// prep-kernel block ranges
#define NBLK_KQ (Bn * Hn * 8)                  // 512  (k/q pack, 128 s each)
#define NBLK_V  (Bn * Hn * 16)                 // 1024
#define NBLK_W  ((HIDn * HIDn) / (256 * 8))    // 128

typedef __bf16 bf16_t;
typedef __bf16 bf16x8 __attribute__((ext_vector_type(8)));
typedef float  f32x4  __attribute__((ext_vector_type(4)));

#define GLDS(g, l) __builtin_amdgcn_global_load_lds(                            \
    (const __attribute__((address_space(1))) void*)(g),                         \
    (__attribute__((address_space(3))) void*)(l), 16, 0, 0)

// ---------------------------------------------------------------------------
// prep R17: pack_qk RESTRUCTURED for coalescing.  Old layout (block per
// (b,s), threads across 16 heads) made every wave write 16 scattered 192B
// segments 196KB apart -- per-wave coalescing broken both ways; prep was
// the inferred ~150us sink (traffic says 15us).  New: block per
// (b, h, 128-s chunk): ts gathered once to LDS, then 12 float4-units per
// thread where consecutive tids read CONTIGUOUS k/q and write CONTIGUOUS
// Kh/Qh (24KB contiguous span per block).  d-mapping identical (d=p*32+hd)
// -> attn unchanged.  pack_v / pack_w(lnw-folded) / sumsq-zero unchanged.
//   blocks [0, 512)         : pack k (+q for s0<512 chunks)
//   blocks [512, 1536)      : pack_v
//   blocks [1536, 1664)     : pack_w  (+ first block zeroes sumsq)
// ---------------------------------------------------------------------------
__global__ __launch_bounds__(256) void prep(
    const float* __restrict__ q, const float* __restrict__ k,
    const float* __restrict__ v, const int* __restrict__ outcell,
    const float* __restrict__ W, const float* __restrict__ lnw,
    bf16_t* __restrict__ Qh, bf16_t* __restrict__ Kh,
    bf16_t* __restrict__ Vt, bf16_t* __restrict__ Wb,
    float* __restrict__ sumsq)
{
    const int blk = blockIdx.x;
    const int tid = threadIdx.x;
    __shared__ float tile[64 * 108];
    __shared__ int ts_sh[128];

    if (blk < NBLK_KQ) {
        // ============ pack k (+q): coalesced (b,h,s-chunk) layout ==========
        const int b = blk >> 7;               // 128 blocks per b
        const int h = (blk >> 3) & 15;
        const int s0 = (blk & 7) << 7;        // 128-s chunk
        if (tid < 128) {
            const int s = s0 + tid;
            ts_sh[tid] = (s < Tn) ? s : outcell[b * EXPn + (s - Tn)];
        }
        __syncthreads();
        const size_t bh = (size_t)b * Hn + h;
#pragma unroll
        for (int j = 0; j < 12; ++j) {
            const int u = tid + 256 * j;      // 0..3071
            const int sl = u / 24, c = u % 24;
            const int p = c >> 3, f = c & 7;
            float4 val = *(const float4*)&k[(size_t)(b * Tn + ts_sh[sl]) * (Pn * HIDn)
                                            + p * HIDn + h * HDn + f * 4];
            bf16_t o4[4] = {(bf16_t)val.x, (bf16_t)val.y, (bf16_t)val.z, (bf16_t)val.w};
            *(uint2*)&Kh[(bh * Sn + s0 + sl) * Dn + c * 4] = *(uint2*)o4;
        }
        if (s0 < Tn) {
#pragma unroll
            for (int j = 0; j < 12; ++j) {
                const int u = tid + 256 * j;
                const int sl = u / 24, c = u % 24;
                const int p = c >> 3, f = c & 7;
                float4 val = *(const float4*)&q[(size_t)(b * Tn + s0 + sl) * (Pn * HIDn)
                                                + p * HIDn + h * HDn + f * 4];
                bf16_t o4[4] = {(bf16_t)(val.x * LOG2E), (bf16_t)(val.y * LOG2E),
                                (bf16_t)(val.z * LOG2E), (bf16_t)(val.w * LOG2E)};
                *(uint2*)&Qh[(bh * Tn + s0 + sl) * Dn + c * 4] = *(uint2*)o4;
            }
        }
    } else if (blk < NBLK_KQ + NBLK_V) {
        // ============ pack_v (R3/R4-verified body) =========================
        const int vblk = blk - NBLK_KQ;
        const int bh = vblk >> 4, s0 = (vblk & 15) << 6;
        const int b = bh >> 4, h = bh & 15;
        if (tid < 64) {
            const int s = s0 + tid;
            ts_sh[tid] = (s < Tn) ? s : outcell[b * EXPn + (s - Tn)];
        }
        __syncthreads();
        for (int u = tid; u < 64 * 24; u += 256) {
            const int sl = u / 24, c = u % 24;
            const int p = c >> 3, f = c & 7;
            float4 val = *(const float4*)&v[(size_t)(b * Tn + ts_sh[sl]) * (Pn * HIDn)
                                            + p * HIDn + h * HDn + f * 4];
            *(float4*)&tile[sl * 108 + c * 4] = val;
        }
        __syncthreads();
        for (int e = tid; e < 96 * 8; e += 256) {
            const int d = e >> 3, g = e & 7;
            bf16_t o8[8];
#pragma unroll
            for (int j = 0; j < 8; ++j) o8[j] = (bf16_t)tile[(g * 8 + j) * 108 + d];
            *(uint4*)&Vt[((size_t)bh * Dn + d) * Sn + s0 + g * 8] = *(uint4*)o8;
        }
    } else {
        // ============ pack_w (lnw folded) + sumsq zero =====================
        const int wblk = blk - (NBLK_KQ + NBLK_V);
        const int i = wblk * 256 + tid;
        const int d0 = (i * 8) & 511;
        float4 f0 = *(const float4*)&W[i * 8];
        float4 f1 = *(const float4*)&W[i * 8 + 4];
        float4 l0 = *(const float4*)&lnw[d0];
        float4 l1 = *(const float4*)&lnw[d0 + 4];
        bf16_t o8[8] = {(bf16_t)(f0.x * l0.x), (bf16_t)(f0.y * l0.y),
                        (bf16_t)(f0.z * l0.z), (bf16_t)(f0.w * l0.w),
                        (bf16_t)(f1.x * l1.x), (bf16_t)(f1.y * l1.y),
                        (bf16_t)(f1.z * l1.z), (bf16_t)(f1.w * l1.w)};
        *(uint4*)&Wb[i * 8] = *(uint4*)o8;
        if (wblk == 0) {
            float4 z = float4{0.f, 0.f, 0.f, 0.f};
            *(float4*)&sumsq[tid * 8]     = z;
            *(float4*)&sumsq[tid * 8 + 4] = z;
        }
    }
}

// ---------------------------------------------------------------------------
// attn_kernel (R16-verified, UNCHANGED): async-staged pipeline, bias/lw
// depth-3, K/V depth-2, counted vmcnt, swapped-operand MFMA, no-max
// softmax, Q pre-scaled by LOG2E, setprio, bf16 Xb output.
// ---------------------------------------------------------------------------
__global__ __launch_bounds__(256, 2) void attn_kernel(
    const bf16_t* __restrict__ Qh, const bf16_t* __restrict__ Kh,
    const bf16_t* __restrict__ Vt, const float* __restrict__ bias,
    const float* __restrict__ lw, bf16_t* __restrict__ Xb,
    float* __restrict__ sumsq)
{
    const int h  = blockIdx.x;
    const int b  = blockIdx.y >> 3;
    const int t0 = (blockIdx.y & 7) << 6;
    const int tid = threadIdx.x;
    const int wv  = tid >> 6;
    const int lane = tid & 63;
    const int l16 = lane & 15;
    const int quad = lane >> 4;

    __shared__ bf16_t KfS[2][6][512];     // K frags f=ct*3+ks   (12 KB)
    __shared__ bf16_t VfS[2][6][512];     // V frags f=dt        (12 KB)
    __shared__ float  BfS[3][4][2][256];  // bias [slot][wv][ct] (24 KB)
    __shared__ float  LfS[3][4][2][256];  // lw   [slot][wv][ct] (24 KB)
    __shared__ bf16_t Ps[4][16 * 40];     // P transpose          (5 KB)

    const size_t bh = (size_t)b * Hn + h;
    const int tb = t0 + wv * 16;

    bf16x8 qf[3];
    {
        const bf16_t* qb = Qh + (bh * Tn + tb + l16) * Dn + quad * 8;
#pragma unroll
        for (int ks = 0; ks < 3; ++ks) qf[ks] = *(const bf16x8*)(qb + ks * 32);
    }
    asm volatile("s_waitcnt vmcnt(0)" ::: "memory");

    int kA, kB, two_k, vA, vB;
    if (wv == 0)      { kA = 0; kB = 1; two_k = 1; vA = 0; vB = 0; }
    else if (wv == 1) { kA = 2; kB = 3; two_k = 1; vA = 1; vB = 0; }
    else if (wv == 2) { kA = 4; kB = 4; two_k = 0; vA = 2; vB = 3; }
    else              { kA = 5; kB = 5; two_k = 0; vA = 4; vB = 5; }

    const float*  gB = bias + (bh * Tn + tb + l16) * (size_t)Sn + quad * 4;
    const float*  gL = lw + ((size_t)b * Tn + tb + l16) * Sn + quad * 4;
    const bf16_t* gKA = Kh + (bh * Sn + (kA / 3) * 16 + l16) * (size_t)Dn + (kA % 3) * 32 + quad * 8;
    const bf16_t* gKB = Kh + (bh * Sn + (kB / 3) * 16 + l16) * (size_t)Dn + (kB % 3) * 32 + quad * 8;
    const bf16_t* gVA = Vt + (bh * Dn + vA * 16 + l16) * (size_t)Sn + quad * 8;
    const bf16_t* gVB = Vt + (bh * Dn + vB * 16 + l16) * (size_t)Sn + quad * 8;

    auto stage_kv = [&](int s0, int buf) {
        GLDS(gKA + (size_t)s0 * Dn, &KfS[buf][kA][0]);
        if (two_k) GLDS(gKB + (size_t)s0 * Dn, &KfS[buf][kB][0]);
        GLDS(gVA + s0, &VfS[buf][vA][0]);
        if (!two_k) GLDS(gVB + s0, &VfS[buf][vB][0]);
    };
    auto stage_bl = [&](int s0, int slot) {
        GLDS(gB + s0,      &BfS[slot][wv][0][0]);
        GLDS(gB + s0 + 16, &BfS[slot][wv][1][0]);
        GLDS(gL + s0,      &LfS[slot][wv][0][0]);
        GLDS(gL + s0 + 16, &LfS[slot][wv][1][0]);
    };

    f32x4 Oacc[6];
#pragma unroll
    for (int i = 0; i < 6; ++i) Oacc[i] = f32x4{0.f, 0.f, 0.f, 0.f};
    float lacc = 0.f;

    stage_bl(0, 0);
    stage_kv(0, 0);
    stage_bl(CH, 1);

    for (int c = 0; c < NCH; ++c) {
        const int buf = c & 1;
        const int slot = c % 3;
        __builtin_amdgcn_sched_barrier(0);
        __builtin_amdgcn_s_barrier();
        __builtin_amdgcn_sched_barrier(0);
        if (c + 1 < NCH) stage_kv((c + 1) * CH, buf ^ 1);
        if (c + 2 < NCH) stage_bl((c + 2) * CH, (c + 2) % 3);
        if (c < NCH - 2)       asm volatile("s_waitcnt vmcnt(11)" ::: "memory");
        else if (c == NCH - 2) asm volatile("s_waitcnt vmcnt(7)" ::: "memory");
        else                   asm volatile("s_waitcnt vmcnt(0)" ::: "memory");
        __builtin_amdgcn_s_barrier();
        __builtin_amdgcn_sched_barrier(0);

        f32x4 BR[2], LR[2];
        BR[0] = *(const f32x4*)&BfS[slot][wv][0][lane * 4];
        BR[1] = *(const f32x4*)&BfS[slot][wv][1][lane * 4];
        LR[0] = *(const f32x4*)&LfS[slot][wv][0][lane * 4];
        LR[1] = *(const f32x4*)&LfS[slot][wv][1][lane * 4];

        f32x4 sc[2];
        __builtin_amdgcn_s_setprio(1);
#pragma unroll
        for (int ct = 0; ct < 2; ++ct) {
            f32x4 acc = f32x4{0.f, 0.f, 0.f, 0.f};
#pragma unroll
            for (int ks = 0; ks < 3; ++ks) {
                bf16x8 kf = *(const bf16x8*)&KfS[buf][ct * 3 + ks][lane * 8];
                acc = __builtin_amdgcn_mfma_f32_16x16x32_bf16(kf, qf[ks], acc, 0, 0, 0);
            }
            sc[ct] = acc;
        }
        __builtin_amdgcn_s_setprio(0);

        float lsum = 0.f;
#pragma unroll
        for (int ct = 0; ct < 2; ++ct) {
            bf16_t o4[4];
#pragma unroll
            for (int r = 0; r < 4; ++r) {
                const float wval = __builtin_fmaf(BR[ct][r], LOG2E, sc[ct][r]);
                const float pe = (LR[ct][r] <= 1e-5f) ? 0.f : exp2f(wval);
                lsum += pe;
                o4[r] = (bf16_t)(pe * LR[ct][r]);
            }
            *(uint2*)&Ps[wv][l16 * 40 + ct * 16 + quad * 4] = *(uint2*)o4;
        }
        lacc += lsum;

        bf16x8 pb = *(const bf16x8*)&Ps[wv][l16 * 40 + quad * 8];
        __builtin_amdgcn_s_setprio(1);
#pragma unroll
        for (int dt = 0; dt < 6; ++dt) {
            bf16x8 vf = *(const bf16x8*)&VfS[buf][dt][lane * 8];
            Oacc[dt] = __builtin_amdgcn_mfma_f32_16x16x32_bf16(vf, pb, Oacc[dt], 0, 0, 0);
        }
        __builtin_amdgcn_s_setprio(0);
    }

    lacc += __shfl_xor(lacc, 16);
    lacc += __shfl_xor(lacc, 32);
    const float invl = 1.0f / lacc;
    const int t = tb + l16;
    float ss = 0.f;
#pragma unroll
    for (int dt = 0; dt < 6; ++dt) {
        const int d0 = dt * 16 + quad * 4;
        bf16_t o4[4];
#pragma unroll
        for (int r = 0; r < 4; ++r) {
            const float o = Oacc[dt][r] * invl;
            ss += o * o;
            o4[r] = (bf16_t)o;
        }
        const int p = d0 >> 5, hd = d0 & 31;
        *(uint2*)&Xb[(((size_t)b * Tn + t) * Pn + p) * HIDn + h * HDn + hd] = *(uint2*)o4;
    }
    ss += __shfl_xor(ss, 16);
    ss += __shfl_xor(ss, 32);
    if (quad == 0) atomicAdd(&sumsq[b * Tn + t], ss);
}

// ---------------------------------------------------------------------------
// out_gemm (R16-verified, UNCHANGED): async-staged pure-bf16 GEMM,
// lnw pre-folded into Wb, inv[m] applied at the f32 accumulator.
// ---------------------------------------------------------------------------
__global__ __launch_bounds__(256, 2) void out_gemm(
    const bf16_t* __restrict__ Xb, const float* __restrict__ sumsq,
    const bf16_t* __restrict__ Wb, float* __restrict__ out)
{
    const int n0 = blockIdx.x * 64;
    const int m0 = blockIdx.y * 64;
    const int tid = threadIdx.x;
    const int wv = tid >> 6, lane = tid & 63, l16 = lane & 15, quad = lane >> 4;

    __shared__ bf16_t Af[2][8][512];   // A frag f = wv*2+ks  (16 KB)
    __shared__ bf16_t Bf[2][8][512];   // B frag f = nt*2+ks  (16 KB)

    const bf16_t* gA0 = Xb + (size_t)(m0 + wv * 16 + l16) * HIDn + 0 * 32 + quad * 8;
    const bf16_t* gA1 = Xb + (size_t)(m0 + wv * 16 + l16) * HIDn + 1 * 32 + quad * 8;
    const bf16_t* gB0 = Wb + (size_t)(n0 + wv * 16 + l16) * HIDn + 0 * 32 + quad * 8;
    const bf16_t* gB1 = Wb + (size_t)(n0 + wv * 16 + l16) * HIDn + 1 * 32 + quad * 8;

    auto stage = [&](int kc, int buf) {
        GLDS(gA0 + kc, &Af[buf][wv * 2 + 0][0]);
        GLDS(gA1 + kc, &Af[buf][wv * 2 + 1][0]);
        GLDS(gB0 + kc, &Bf[buf][wv * 2 + 0][0]);
        GLDS(gB1 + kc, &Bf[buf][wv * 2 + 1][0]);
    };

    f32x4 acc[4];
#pragma unroll
    for (int i = 0; i < 4; ++i) acc[i] = f32x4{0.f, 0.f, 0.f, 0.f};

    stage(0, 0);

    for (int c = 0; c < 8; ++c) {
        const int buf = c & 1;
        __builtin_amdgcn_sched_barrier(0);
        __builtin_amdgcn_s_barrier();
        __builtin_amdgcn_sched_barrier(0);
        if (c + 1 < 8) {
            stage((c + 1) * 64, buf ^ 1);
            asm volatile("s_waitcnt vmcnt(4)" ::: "memory");
        } else {
            asm volatile("s_waitcnt vmcnt(0)" ::: "memory");
        }
        __builtin_amdgcn_s_barrier();
        __builtin_amdgcn_sched_barrier(0);

        __builtin_amdgcn_s_setprio(1);
#pragma unroll
        for (int ks = 0; ks < 2; ++ks) {
            bf16x8 a = *(const bf16x8*)&Af[buf][wv * 2 + ks][lane * 8];
#pragma unroll
            for (int nt = 0; nt < 4; ++nt) {
                bf16x8 bb = *(const bf16x8*)&Bf[buf][nt * 2 + ks][lane * 8];
                acc[nt] = __builtin_amdgcn_mfma_f32_16x16x32_bf16(a, bb, acc[nt], 0, 0, 0);
            }
        }
        __builtin_amdgcn_s_setprio(0);
    }

    float invm[4];
#pragma unroll
    for (int r = 0; r < 4; ++r) {
        const int m = m0 + wv * 16 + quad * 4 + r;
        invm[r] = rsqrtf(sumsq[m / 3] * (1.0f / HIDn) + 1e-3f);
    }
#pragma unroll
    for (int nt = 0; nt < 4; ++nt)
#pragma unroll
        for (int r = 0; r < 4; ++r) {
            const int m = m0 + wv * 16 + quad * 4 + r;
            const int n = n0 + nt * 16 + l16;
            out[(size_t)m * HIDn + n] = acc[nt][r] * invm[r];
        }
}

// ---------------------------------------------------------------------------
// Workspace: Qh@0 (6291456) | Kh@6291456 (12582912) | Vt@18874368 (12582912) |
// Xb@31457280 (6291456) | Wb@37748736 (524288) | sumsq@38273024 (8192)
// ---------------------------------------------------------------------------
extern "C" void kernel_launch(void* const* d_in, const int* in_sizes, int n_in,
                              void* d_out, int out_size, void* d_ws, size_t ws_size,
                              hipStream_t stream)
{
    const float* q    = (const float*)d_in[0];
    const float* k    = (const float*)d_in[1];
    const float* v    = (const float*)d_in[2];
    const float* bias = (const float*)d_in[3];
    const int*   outcell = (const int*)d_in[5];
    const float* lw   = (const float*)d_in[6];
    const float* W    = (const float*)d_in[8];
    const float* lnw  = (const float*)d_in[9];
    float* out = (float*)d_out;

    char* ws = (char*)d_ws;
    bf16_t* Qh   = (bf16_t*)(ws);
    bf16_t* Kh   = (bf16_t*)(ws + 6291456);
    bf16_t* Vt   = (bf16_t*)(ws + 18874368);
    bf16_t* Xb   = (bf16_t*)(ws + 31457280);
    bf16_t* Wb   = (bf16_t*)(ws + 37748736);
    float*  sumsq = (float*)(ws + 38273024);

    prep<<<dim3(NBLK_KQ + NBLK_V + NBLK_W), 256, 0, stream>>>(
        q, k, v, outcell, W, lnw, Qh, Kh, Vt, Wb, sumsq);
    attn_kernel<<<dim3(Hn, Bn * (Tn / 64)), 256, 0, stream>>>(Qh, Kh, Vt, bias, lw, Xb, sumsq);
    out_gemm<<<dim3(HIDn / 64, (Bn * Tn * Pn) / 64), 256, 0, stream>>>(Xb, sumsq, Wb, out);
}